// Round 7
// baseline (367.461 us; speedup 1.0000x reference)
//
#include <hip/hip_runtime.h>
#include <hip/hip_bf16.h>

#define D_DIM 512
#define H_DIM 512
#define G_SEG 1024
#define BM    64

typedef __attribute__((ext_vector_type(8))) short bf16x8;
typedef __attribute__((ext_vector_type(4))) float f32x4;
typedef unsigned int u32;
typedef unsigned short u16;

// ---- workspace ----
#define WS_S   0         // G f32
#define WS_WB  8192      // 512 KB bf16 W in MFMA-fragment granule layout

// ---- LDS ----  As: 64 rows x 1024B (bf16 x 512, XOR-swizzled)
#define AS_BYTES  (BM * 1024)
#define BETA_OFF  AS_BYTES
#define EBS_OFF   (BETA_OFF + 8 * BM * 4)
#define SIDX_OFF  (EBS_OFF + BM * 4)
#define LDS_TOTAL (SIDX_OFF + BM * 4)

static __device__ __forceinline__ u16 f2bf(float f) {
    __hip_bfloat16 h = __float2bfloat16(f);
    return *(u16*)&h;
}
static __device__ __forceinline__ float bf2f(u16 u) {
    return __uint_as_float(((u32)u) << 16);
}
static __device__ __forceinline__ float fast_tanh(float x) {
    float e = exp2f(x * 2.885390081777927f);   // e^(2x)
    return 1.0f - 2.0f * __builtin_amdgcn_rcpf(e + 1.0f);
}

// ---- W fp32 -> bf16 in granule layout: granule(k32, c, lhi) = W[c][k32*32 + lhi*8 .. +8]
__global__ __launch_bounds__(256)
void cvt_w(const float* __restrict__ W, u16* __restrict__ Wb) {
    int t   = blockIdx.x * 256 + threadIdx.x;   // 32768 granules
    int lhi = t & 3;
    int c   = (t >> 2) & 511;
    int k32 = t >> 11;
    const float* src = W + (size_t)c * 512 + k32 * 32 + lhi * 8;
    float4 f0 = *(const float4*)(src);
    float4 f1 = *(const float4*)(src + 4);
    u16 h[8];
    h[0]=f2bf(f0.x); h[1]=f2bf(f0.y); h[2]=f2bf(f0.z); h[3]=f2bf(f0.w);
    h[4]=f2bf(f1.x); h[5]=f2bf(f1.y); h[6]=f2bf(f1.z); h[7]=f2bf(f1.w);
    *(uint4*)(Wb + (size_t)t * 8) = *(uint4*)h;
}

// ---- fused: GEMM(64 x 512 x 512) + tanh*V reduce + exp + segment sums ----
// 8 waves = 8 col-groups of 64; each wave: 64 rows x 64 cols -> acc[4][4].
// Full A-tile staged up front; K-loop is barrier-free (no vmcnt(0) drains).
__global__ __launch_bounds__(512, 4)
void fused(const float* __restrict__ E, const int* __restrict__ BI,
           const u16* __restrict__ Wb, const float* __restrict__ V,
           float* __restrict__ out, float* __restrict__ S)
{
    extern __shared__ char smem[];
    const int tid = threadIdx.x;
    const int nodeBase = blockIdx.x * BM;
    const int l   = tid & 63;
    const int w   = tid >> 6;     // col group: cols [w*64, w*64+64)
    const int l15 = l & 15;
    const int lhi = l >> 4;

    const float* Eb = E + (size_t)nodeBase * 512;
    const int arow = tid >> 3;    // 0..63
    const int aj   = tid & 7;

    f32x4 acc[4][4];
#pragma unroll
    for (int m = 0; m < 4; ++m)
#pragma unroll
        for (int n = 0; n < 4; ++n) acc[m][n] = (f32x4){0.f, 0.f, 0.f, 0.f};

    // per-lane b-frag byte offset within a 32-k (32KB) W slab; stride per n = 1024B
    const int bOffBase = ((w * 64 + l15) * 4 + lhi) * 16;

    // ---- stage the FULL 64x512 A-tile: 2 phases x (8 float4 loads -> cvt -> 4 swizzled b128 writes)
    {
        const float* prow = Eb + (size_t)arow * 512 + aj * 8;
        const int bytebase = arow * 1024;
        const int swz = (arow & 7) << 4;
#pragma unroll 1
        for (int ph = 0; ph < 2; ++ph) {
            float4 L[8];
#pragma unroll
            for (int q = 0; q < 4; ++q) {          // ks = ph*4 + q
                const float* p = prow + (ph * 4 + q) * 64;
                L[2 * q]     = *(const float4*)p;
                L[2 * q + 1] = *(const float4*)(p + 4);
            }
#pragma unroll
            for (int q = 0; q < 4; ++q) {
                u16 h[8];
                h[0]=f2bf(L[2*q].x);   h[1]=f2bf(L[2*q].y);
                h[2]=f2bf(L[2*q].z);   h[3]=f2bf(L[2*q].w);
                h[4]=f2bf(L[2*q+1].x); h[5]=f2bf(L[2*q+1].y);
                h[6]=f2bf(L[2*q+1].z); h[7]=f2bf(L[2*q+1].w);
                int byte0 = bytebase + (((ph * 4 + q) * 128 + aj * 16) ^ swz);
                *(uint4*)(smem + byte0) = *(uint4*)h;
            }
        }
    }
    __syncthreads();

    // ---- barrier-free K-loop: 16 steps of 32 k
#pragma unroll 1
    for (int kk = 0; kk < 16; ++kk) {
        const char* Wsub = (const char*)Wb + ((size_t)kk << 15);
        bf16x8 b[4];
#pragma unroll
        for (int n = 0; n < 4; ++n)
            b[n] = *(const bf16x8*)(Wsub + bOffBase + n * 1024);
        bf16x8 a[4];
        const int kbyte = kk * 64 + lhi * 16;
#pragma unroll
        for (int m = 0; m < 4; ++m) {
            int row = m * 16 + l15;
            a[m] = *(const bf16x8*)(smem + row * 1024 + (kbyte ^ ((row & 7) << 4)));
        }
#pragma unroll
        for (int m = 0; m < 4; ++m)
#pragma unroll
            for (int n = 0; n < 4; ++n)
                acc[m][n] = __builtin_amdgcn_mfma_f32_16x16x32_bf16(a[m], b[n], acc[m][n], 0, 0, 0);
    }

    // ---- epilogue: beta-partial[row] = sum_{cols of this wave} V[c] * tanh(z[row][c])
    float Vv[4];
#pragma unroll
    for (int n = 0; n < 4; ++n)
        Vv[n] = V[w * 64 + n * 16 + l15];

    float bsum[4][4];
#pragma unroll
    for (int m = 0; m < 4; ++m)
#pragma unroll
        for (int r = 0; r < 4; ++r) {
            float s = 0.f;
#pragma unroll
            for (int n = 0; n < 4; ++n)
                s += Vv[n] * fast_tanh(acc[m][n][r]);
            bsum[m][r] = s;
        }
#pragma unroll
    for (int off = 1; off <= 8; off <<= 1)
#pragma unroll
        for (int m = 0; m < 4; ++m)
#pragma unroll
            for (int r = 0; r < 4; ++r)
                bsum[m][r] += __shfl_xor(bsum[m][r], off, 64);

    float* betaP = (float*)(smem + BETA_OFF);   // [8 col-groups][64 rows]
    if (l15 == 0) {
#pragma unroll
        for (int m = 0; m < 4; ++m)
#pragma unroll
            for (int r = 0; r < 4; ++r)
                betaP[w * BM + m * 16 + lhi * 4 + r] = bsum[m][r];
    }
    __syncthreads();

    // ---- eb = exp(beta); S[g] += eb (wave-aggregated; rows sorted)
    float* ebs  = (float*)(smem + EBS_OFF);
    int*   sidx = (int*)(smem + SIDX_OFF);
    if (tid < BM) {
        float beta = 0.f;
#pragma unroll
        for (int j = 0; j < 8; ++j)
            beta += betaP[j * BM + tid];
        float eb = expf(beta);
        ebs[tid] = eb;
        int g = BI[nodeBase + tid];
        sidx[tid] = g;
        int g0 = __shfl(g, 0, 64);
        if (__all(g == g0)) {
            float s = eb;
#pragma unroll
            for (int off = 1; off <= 32; off <<= 1)
                s += __shfl_xor(s, off, 64);
            if (l == 0) atomicAdd(&S[g], s);
        } else {
            atomicAdd(&S[g], eb);
        }
    }
    __syncthreads();

    // ---- weighted segment sum: thread t = column t over all 64 rows.
    // Lane-contiguous atomics coalesce into full lines (round-4 lesson).
    {
        const int c = tid;     // 512 cols
        float a = 0.f;
        int gcur = sidx[0];
        for (int r = 0; r < BM; ++r) {
            int g = sidx[r];                     // wave-uniform
            if (g != gcur) {
                atomicAdd(&out[(size_t)gcur * 512 + c], a);
                a = 0.f; gcur = g;
            }
            u16 v = *(const u16*)(smem + r * 1024 + ((2 * c) ^ ((r & 7) << 4)));
            a += ebs[r] * bf2f(v);
        }
        atomicAdd(&out[(size_t)gcur * 512 + c], a);
    }
}

__global__ __launch_bounds__(256)
void finalize_kernel(float* __restrict__ out, const float* __restrict__ S) {
    int idx = blockIdx.x * 256 + threadIdx.x;
    float s = S[idx >> 9];
    float v = out[idx];
    out[idx] = (s != 0.f) ? v * __builtin_amdgcn_rcpf(s) : 0.f;
}

extern "C" void kernel_launch(void* const* d_in, const int* in_sizes, int n_in,
                              void* d_out, int out_size, void* d_ws, size_t ws_size,
                              hipStream_t stream) {
    const float* E  = (const float*)d_in[0];
    const int*   BI = (const int*)d_in[1];
    const float* W  = (const float*)d_in[2];
    const float* V  = (const float*)d_in[3];
    float* out = (float*)d_out;
    char*  ws  = (char*)d_ws;
    const int Ntot = in_sizes[0] / D_DIM;

    float* S  = (float*)(ws + WS_S);
    u16*   Wb = (u16*)(ws + WS_WB);

    hipMemsetAsync(S, 0, G_SEG * 4, stream);
    hipMemsetAsync(out, 0, (size_t)out_size * 4, stream);
    hipFuncSetAttribute((const void*)fused,
                        hipFuncAttributeMaxDynamicSharedMemorySize, LDS_TOTAL);

    cvt_w<<<128, 256, 0, stream>>>(W, Wb);
    fused<<<Ntot / BM, 512, LDS_TOTAL, stream>>>(E, BI, Wb, V, out, S);
    finalize_kernel<<<out_size / 256, 256, 0, stream>>>(out, S);
}

// Round 8
// 356.325 us; speedup vs baseline: 1.0313x; 1.0313x over previous
//
#include <hip/hip_runtime.h>
#include <hip/hip_bf16.h>

#define D_DIM 512
#define H_DIM 512
#define G_SEG 1024
#define BM    64

typedef __attribute__((ext_vector_type(8))) short bf16x8;
typedef __attribute__((ext_vector_type(4))) float f32x4;
typedef unsigned int u32;
typedef unsigned short u16;

// ---- workspace ----
#define WS_S   0         // G f32
#define WS_WB  8192      // 512 KB bf16 W in MFMA-fragment granule layout

// ---- LDS layout ----
#define AS_BYTES  (BM * 1024)                 // 64 rows x 1024B bf16, XOR-swizzled
#define BETA_OFF  AS_BYTES                    // 4 col-groups x 64 f32
#define EBS_OFF   (BETA_OFF + 4 * BM * 4)
#define SIDX_OFF  (EBS_OFF + BM * 4)
#define SCR_OFF   (SIDX_OFF + BM * 4)         // 4 waves x 512 f32 flush scratch
#define LDS_TOTAL (SCR_OFF + 4 * 512 * 4)

static __device__ __forceinline__ u16 f2bf(float f) {
    __hip_bfloat16 h = __float2bfloat16(f);
    return *(u16*)&h;
}
static __device__ __forceinline__ float bf2f(u16 u) {
    return __uint_as_float(((u32)u) << 16);
}
static __device__ __forceinline__ float fast_tanh(float x) {
    float e = exp2f(x * 2.885390081777927f);   // e^(2x)
    return 1.0f - 2.0f * __builtin_amdgcn_rcpf(e + 1.0f);
}
static __device__ __forceinline__ void pack8(const float4& a, const float4& b, void* dst) {
    u16 h[8];
    h[0]=f2bf(a.x); h[1]=f2bf(a.y); h[2]=f2bf(a.z); h[3]=f2bf(a.w);
    h[4]=f2bf(b.x); h[5]=f2bf(b.y); h[6]=f2bf(b.z); h[7]=f2bf(b.w);
    *(uint4*)dst = *(uint4*)h;
}

// ---- W fp32 -> bf16 granule layout: byte ((k32*512 + c)*4 + lhi)*16 = W[c][k32*32+lhi*8 ..+8]
__global__ __launch_bounds__(256)
void cvt_w(const float* __restrict__ W, u16* __restrict__ Wb) {
    int t   = blockIdx.x * 256 + threadIdx.x;   // 32768 granules
    int lhi = t & 3;
    int c   = (t >> 2) & 511;
    int k32 = t >> 11;
    const float* src = W + (size_t)c * 512 + k32 * 32 + lhi * 8;
    float4 f0 = *(const float4*)(src);
    float4 f1 = *(const float4*)(src + 4);
    pack8(f0, f1, Wb + (size_t)t * 8);
}

// ---- fused: GEMM(64 x 512 x 512) + tanh*V reduce + exp + segment sums ----
// 4 waves x (64 rows x 128 cols): acc[4][8]. A staged once; K-loop barrier-free
// with bA/bB register double-buffering of W fragments (L2-resident).
__global__ __launch_bounds__(256, 2)
void fused(const float* __restrict__ E, const int* __restrict__ BI,
           const u16* __restrict__ Wb, const float* __restrict__ V,
           float* __restrict__ out, float* __restrict__ S)
{
    extern __shared__ char smem[];
    const int tid = threadIdx.x;
    const int nodeBase = blockIdx.x * BM;
    const int l   = tid & 63;
    const int w   = tid >> 6;     // col group: cols [w*128, w*128+128)
    const int l15 = l & 15;
    const int lhi = l >> 4;

    const float* Eb = E + (size_t)nodeBase * 512;

    // ---- stage the FULL 64x512 A-tile (fp32 -> bf16, swizzled), 4 batches ----
#pragma unroll 1
    for (int p = 0; p < 4; ++p) {
        float4 L[8];
        const int ci0 = p * 1024 + tid * 4;     // ushort8-chunk index
#pragma unroll
        for (int j = 0; j < 4; ++j) {
            int ci = ci0 + j;
            int row = ci >> 6, cc = ci & 63;
            const float* src = Eb + (size_t)row * 512 + cc * 8;
            L[2*j]   = *(const float4*)src;
            L[2*j+1] = *(const float4*)(src + 4);
        }
#pragma unroll
        for (int j = 0; j < 4; ++j) {
            int ci = ci0 + j;
            int row = ci >> 6, cc = ci & 63;
            int byte0 = row * 1024 + ((cc * 16) ^ ((row & 7) << 4));
            pack8(L[2*j], L[2*j+1], smem + byte0);
        }
    }
    __syncthreads();

    // ---- K-loop: 16 steps of 32k, b double-buffered in registers ----
    f32x4 acc[4][8];
#pragma unroll
    for (int m = 0; m < 4; ++m)
#pragma unroll
        for (int n = 0; n < 8; ++n) acc[m][n] = (f32x4){0.f, 0.f, 0.f, 0.f};

    const int bOffBase = ((w * 128 + l15) * 4 + lhi) * 16;   // + n*1024
    const char* Wbb = (const char*)Wb;

    bf16x8 bA[8], bB[8];
#pragma unroll
    for (int n = 0; n < 8; ++n)
        bA[n] = *(const bf16x8*)(Wbb + bOffBase + n * 1024);

#pragma unroll 1
    for (int kk2 = 0; kk2 < 8; ++kk2) {
        {   // half A: compute kk=2*kk2 with bA; prefetch bB for kk+1
            const char* Wn = Wbb + ((size_t)(2 * kk2 + 1) << 15);
#pragma unroll
            for (int n = 0; n < 8; ++n)
                bB[n] = *(const bf16x8*)(Wn + bOffBase + n * 1024);
            bf16x8 a[4];
            const int kbyte = (2 * kk2) * 64 + lhi * 16;
#pragma unroll
            for (int m = 0; m < 4; ++m) {
                int row = m * 16 + l15;
                a[m] = *(const bf16x8*)(smem + row * 1024 + (kbyte ^ ((row & 7) << 4)));
            }
#pragma unroll
            for (int m = 0; m < 4; ++m)
#pragma unroll
                for (int n = 0; n < 8; ++n)
                    acc[m][n] = __builtin_amdgcn_mfma_f32_16x16x32_bf16(a[m], bA[n], acc[m][n], 0, 0, 0);
        }
        {   // half B: compute kk=2*kk2+1 with bB; prefetch bA for next kk2
            if (kk2 < 7) {
                const char* Wn = Wbb + ((size_t)(2 * kk2 + 2) << 15);
#pragma unroll
                for (int n = 0; n < 8; ++n)
                    bA[n] = *(const bf16x8*)(Wn + bOffBase + n * 1024);
            }
            bf16x8 a[4];
            const int kbyte = (2 * kk2 + 1) * 64 + lhi * 16;
#pragma unroll
            for (int m = 0; m < 4; ++m) {
                int row = m * 16 + l15;
                a[m] = *(const bf16x8*)(smem + row * 1024 + (kbyte ^ ((row & 7) << 4)));
            }
#pragma unroll
            for (int m = 0; m < 4; ++m)
#pragma unroll
                for (int n = 0; n < 8; ++n)
                    acc[m][n] = __builtin_amdgcn_mfma_f32_16x16x32_bf16(a[m], bB[n], acc[m][n], 0, 0, 0);
        }
    }

    // ---- epilogue: beta-partial[row] = sum over this wave's 128 cols of V*tanh
    float Vv[8];
#pragma unroll
    for (int n = 0; n < 8; ++n)
        Vv[n] = V[w * 128 + n * 16 + l15];

    float bsum[4][4];
#pragma unroll
    for (int m = 0; m < 4; ++m)
#pragma unroll
        for (int r = 0; r < 4; ++r) {
            float s = 0.f;
#pragma unroll
            for (int n = 0; n < 8; ++n)
                s += Vv[n] * fast_tanh(acc[m][n][r]);
            bsum[m][r] = s;
        }
#pragma unroll
    for (int off = 1; off <= 8; off <<= 1)
#pragma unroll
        for (int m = 0; m < 4; ++m)
#pragma unroll
            for (int r = 0; r < 4; ++r)
                bsum[m][r] += __shfl_xor(bsum[m][r], off, 64);

    float* betaP = (float*)(smem + BETA_OFF);   // [4 col-groups][64 rows]
    if (l15 == 0) {
#pragma unroll
        for (int m = 0; m < 4; ++m)
#pragma unroll
            for (int r = 0; r < 4; ++r)
                betaP[w * BM + m * 16 + lhi * 4 + r] = bsum[m][r];
    }
    __syncthreads();

    // ---- eb = exp(beta); S[g] += eb (wave 0; rows sorted) ----
    float* ebs  = (float*)(smem + EBS_OFF);
    int*   sidx = (int*)(smem + SIDX_OFF);
    if (tid < BM) {
        float beta = betaP[tid] + betaP[BM + tid] + betaP[2 * BM + tid] + betaP[3 * BM + tid];
        float eb = expf(beta);
        ebs[tid] = eb;
        int g = BI[nodeBase + tid];
        sidx[tid] = g;
        int g0 = __shfl(g, 0, 64);
        if (__all(g == g0)) {
            float s = eb;
#pragma unroll
            for (int off = 1; off <= 32; off <<= 1)
                s += __shfl_xor(s, off, 64);
            if (l == 0) atomicAdd(&S[g], s);
        } else {
            atomicAdd(&S[g], eb);
        }
    }
    __syncthreads();

    // ---- weighted segment sum: wave w owns rows [16w,16w+16); lane l cols [8l,8l+8).
    // Vector b128 reads; flushes transpose through per-wave LDS scratch so the
    // global atomics are lane-contiguous (round-4 lesson).
    {
        float* scr = (float*)(smem + SCR_OFF) + w * 512;
        const int rbase = w * 16;
        float a8[8];
#pragma unroll
        for (int j = 0; j < 8; ++j) a8[j] = 0.f;
        int gcur = sidx[rbase];

#pragma unroll 1
        for (int rr = 0; rr < 16; ++rr) {
            int r = rbase + rr;
            int g = sidx[r];                     // wave-uniform
            if (g != gcur) {
                *(float4*)(scr + l * 8)     = make_float4(a8[0], a8[1], a8[2], a8[3]);
                *(float4*)(scr + l * 8 + 4) = make_float4(a8[4], a8[5], a8[6], a8[7]);
                asm volatile("s_waitcnt lgkmcnt(0)" ::: "memory");
#pragma unroll
                for (int j = 0; j < 8; ++j)
                    atomicAdd(&out[(size_t)gcur * 512 + j * 64 + l], scr[j * 64 + l]);
#pragma unroll
                for (int j = 0; j < 8; ++j) a8[j] = 0.f;
                gcur = g;
            }
            float wgt = ebs[r];
            bf16x8 v = *(const bf16x8*)(smem + r * 1024 + ((l * 16) ^ ((r & 7) << 4)));
#pragma unroll
            for (int j = 0; j < 8; ++j)
                a8[j] += wgt * bf2f((u16)v[j]);
        }
        // final flush
        *(float4*)(scr + l * 8)     = make_float4(a8[0], a8[1], a8[2], a8[3]);
        *(float4*)(scr + l * 8 + 4) = make_float4(a8[4], a8[5], a8[6], a8[7]);
        asm volatile("s_waitcnt lgkmcnt(0)" ::: "memory");
#pragma unroll
        for (int j = 0; j < 8; ++j)
            atomicAdd(&out[(size_t)gcur * 512 + j * 64 + l], scr[j * 64 + l]);
    }
}

__global__ __launch_bounds__(256)
void finalize_kernel(float* __restrict__ out, const float* __restrict__ S) {
    int idx = blockIdx.x * 256 + threadIdx.x;
    float s = S[idx >> 9];
    float v = out[idx];
    out[idx] = (s != 0.f) ? v * __builtin_amdgcn_rcpf(s) : 0.f;
}

extern "C" void kernel_launch(void* const* d_in, const int* in_sizes, int n_in,
                              void* d_out, int out_size, void* d_ws, size_t ws_size,
                              hipStream_t stream) {
    const float* E  = (const float*)d_in[0];
    const int*   BI = (const int*)d_in[1];
    const float* W  = (const float*)d_in[2];
    const float* V  = (const float*)d_in[3];
    float* out = (float*)d_out;
    char*  ws  = (char*)d_ws;
    const int Ntot = in_sizes[0] / D_DIM;

    float* S  = (float*)(ws + WS_S);
    u16*   Wb = (u16*)(ws + WS_WB);

    hipMemsetAsync(S, 0, G_SEG * 4, stream);
    hipMemsetAsync(out, 0, (size_t)out_size * 4, stream);
    hipFuncSetAttribute((const void*)fused,
                        hipFuncAttributeMaxDynamicSharedMemorySize, LDS_TOTAL);

    cvt_w<<<128, 256, 0, stream>>>(W, Wb);
    fused<<<Ntot / BM, 256, LDS_TOTAL, stream>>>(E, BI, Wb, V, out, S);
    finalize_kernel<<<out_size / 256, 256, 0, stream>>>(out, S);
}